// Round 1
// baseline (335.649 us; speedup 1.0000x reference)
//
#include <hip/hip_runtime.h>

// Voxelizer3D: out[f][z][y][x] = sum over atoms a (masked: all coords != 0)
// whose center cell c(a) is within Chebyshev distance 1 of (x,y,z), of feat[a][f].
// Implemented as: center-cell histogram (atomic scatter) + 3x3x3 box convolution.

constexpr int VOL   = 48;
constexpr int FEATD = 19;
constexpr int VOL3  = VOL * VOL * VOL;

// monotonic float -> uint key (total order preserved)
__device__ __forceinline__ unsigned fkey(float f) {
    unsigned u = __float_as_uint(f);
    return (u & 0x80000000u) ? ~u : (u | 0x80000000u);
}
__device__ __forceinline__ float funkey(unsigned k) {
    unsigned u = (k & 0x80000000u) ? (k & 0x7fffffffu) : ~k;
    return __uint_as_float(u);
}

__global__ void vox_minmax(const float* __restrict__ xyz, int n,
                           unsigned* __restrict__ keys) {
    int i = blockIdx.x * blockDim.x + threadIdx.x;
    unsigned kmin[3] = {0xFFFFFFFFu, 0xFFFFFFFFu, 0xFFFFFFFFu};
    unsigned kmax[3] = {0u, 0u, 0u};
    if (i < n) {
        float x = xyz[3 * i + 0], y = xyz[3 * i + 1], z = xyz[3 * i + 2];
        if (x != 0.f && y != 0.f && z != 0.f) {
            unsigned kx = fkey(x), ky = fkey(y), kz = fkey(z);
            kmin[0] = kx; kmin[1] = ky; kmin[2] = kz;
            kmax[0] = kx; kmax[1] = ky; kmax[2] = kz;
        }
    }
    // wave-64 butterfly reduce
    #pragma unroll
    for (int o = 32; o; o >>= 1) {
        #pragma unroll
        for (int c = 0; c < 3; c++) {
            unsigned omin = __shfl_xor(kmin[c], o, 64);
            unsigned omax = __shfl_xor(kmax[c], o, 64);
            kmin[c] = kmin[c] < omin ? kmin[c] : omin;
            kmax[c] = kmax[c] > omax ? kmax[c] : omax;
        }
    }
    if ((threadIdx.x & 63) == 0) {
        #pragma unroll
        for (int c = 0; c < 3; c++) {
            atomicMin(&keys[c], kmin[c]);
            atomicMax(&keys[3 + c], kmax[c]);
        }
    }
}

__global__ void vox_scatter(const float* __restrict__ xyz,
                            const float* __restrict__ feat, int n,
                            const unsigned* __restrict__ keys,
                            float* __restrict__ center) {
    int i = blockIdx.x * blockDim.x + threadIdx.x;
    if (i >= n) return;
    float x = xyz[3 * i + 0], y = xyz[3 * i + 1], z = xyz[3 * i + 2];
    if (x == 0.f || y == 0.f || z == 0.f) return;  // reference mask
    float mnx = funkey(keys[0]), mny = funkey(keys[1]), mnz = funkey(keys[2]);
    float mxx = funkey(keys[3]), mxy = funkey(keys[4]), mxz = funkey(keys[5]);
    // exact op-order of reference: (x - min) / (max - min) * 47, f32, truncate
    int cx = (int)((x - mnx) / (mxx - mnx) * 47.0f);
    int cy = (int)((y - mny) / (mxy - mny) * 47.0f);
    int cz = (int)((z - mnz) / (mxz - mnz) * 47.0f);
    int cell = (cz * VOL + cy) * VOL + cx;
    const float* fr = feat + (size_t)i * FEATD;
    #pragma unroll
    for (int f = 0; f < FEATD; f++)
        atomicAdd(&center[f * VOL3 + cell], fr[f]);
}

__global__ void vox_conv(const float* __restrict__ center,
                         float* __restrict__ out, int total) {
    int idx = blockIdx.x * blockDim.x + threadIdx.x;
    if (idx >= total) return;
    int x = idx % VOL;
    int t = idx / VOL;
    int y = t % VOL;  t /= VOL;
    int z = t % VOL;
    int f = t / VOL;
    const float* cf = center + (size_t)f * VOL3;
    float s = 0.f;
    for (int dz = -1; dz <= 1; dz++) {
        int zz = z + dz; if ((unsigned)zz >= (unsigned)VOL) continue;
        for (int dy = -1; dy <= 1; dy++) {
            int yy = y + dy; if ((unsigned)yy >= (unsigned)VOL) continue;
            const float* row = cf + (zz * VOL + yy) * VOL;
            #pragma unroll
            for (int dx = -1; dx <= 1; dx++) {
                int xx = x + dx; if ((unsigned)xx >= (unsigned)VOL) continue;
                s += row[xx];
            }
        }
    }
    out[idx] = s;
}

extern "C" void kernel_launch(void* const* d_in, const int* in_sizes, int n_in,
                              void* d_out, int out_size, void* d_ws, size_t ws_size,
                              hipStream_t stream) {
    const float* xyz  = (const float*)d_in[0];
    const float* feat = (const float*)d_in[1];
    float* out = (float*)d_out;
    int n = in_sizes[0] / 3;

    unsigned* keys = (unsigned*)d_ws;
    float* center = (float*)((char*)d_ws + 256);

    // re-initialize workspace every call (harness does not re-poison)
    hipMemsetAsync(keys, 0xFF, 3 * sizeof(unsigned), stream);      // min keys -> max key val
    hipMemsetAsync(keys + 3, 0x00, 3 * sizeof(unsigned), stream);  // max keys -> min key val
    hipMemsetAsync(center, 0, (size_t)FEATD * VOL3 * sizeof(float), stream);

    const int b = 256;
    vox_minmax<<<(n + b - 1) / b, b, 0, stream>>>(xyz, n, keys);
    vox_scatter<<<(n + b - 1) / b, b, 0, stream>>>(xyz, feat, n, keys, center);
    const int total = FEATD * VOL3;
    vox_conv<<<(total + b - 1) / b, b, 0, stream>>>(center, out, total);
}

// Round 2
// 200.522 us; speedup vs baseline: 1.6739x; 1.6739x over previous
//
#include <hip/hip_runtime.h>

// Voxelizer3D: out[f][z][y][x] = sum over masked atoms (all coords != 0) whose
// center cell is within Chebyshev distance 1 of (x,y,z), of feat[a][f].
// Pipeline: minmax (block-reduced) -> hashed-atomic center histogram ->
// unhash remap -> 3x3x3 box convolution.

constexpr int VOL   = 48;
constexpr int FEATD = 19;
constexpr int VOL3  = VOL * VOL * VOL;           // 110592
constexpr unsigned HPLANE = 131072;              // 2^17 padded hashed plane
constexpr unsigned HMUL   = 2654435761u;         // odd -> bijection mod 2^17

__device__ __forceinline__ unsigned fkey(float f) {
    unsigned u = __float_as_uint(f);
    return (u & 0x80000000u) ? ~u : (u | 0x80000000u);
}
__device__ __forceinline__ float funkey(unsigned k) {
    unsigned u = (k & 0x80000000u) ? (k & 0x7fffffffu) : ~k;
    return __uint_as_float(u);
}
__device__ __forceinline__ unsigned hcell(int cell) {
    return ((unsigned)cell * HMUL) & (HPLANE - 1u);
}

// ---- stage 1: min/max of masked coords, 64 blocks, block-level reduce ----
__global__ __launch_bounds__(1024) void vox_minmax(const float* __restrict__ xyz,
                                                   int n, unsigned* __restrict__ keys) {
    __shared__ unsigned smin[16][3], smax[16][3];
    unsigned kmin[3] = {~0u, ~0u, ~0u};
    unsigned kmax[3] = {0u, 0u, 0u};
    for (int i = blockIdx.x * blockDim.x + threadIdx.x; i < n;
         i += gridDim.x * blockDim.x) {
        float x = xyz[3 * i + 0], y = xyz[3 * i + 1], z = xyz[3 * i + 2];
        if (x != 0.f && y != 0.f && z != 0.f) {
            unsigned k[3] = {fkey(x), fkey(y), fkey(z)};
            #pragma unroll
            for (int c = 0; c < 3; c++) {
                kmin[c] = kmin[c] < k[c] ? kmin[c] : k[c];
                kmax[c] = kmax[c] > k[c] ? kmax[c] : k[c];
            }
        }
    }
    #pragma unroll
    for (int o = 32; o; o >>= 1) {
        #pragma unroll
        for (int c = 0; c < 3; c++) {
            unsigned omin = __shfl_xor(kmin[c], o, 64);
            unsigned omax = __shfl_xor(kmax[c], o, 64);
            kmin[c] = kmin[c] < omin ? kmin[c] : omin;
            kmax[c] = kmax[c] > omax ? kmax[c] : omax;
        }
    }
    int wave = threadIdx.x >> 6;
    if ((threadIdx.x & 63) == 0) {
        #pragma unroll
        for (int c = 0; c < 3; c++) { smin[wave][c] = kmin[c]; smax[wave][c] = kmax[c]; }
    }
    __syncthreads();
    if (threadIdx.x == 0) {
        int nw = blockDim.x >> 6;
        #pragma unroll
        for (int c = 0; c < 3; c++) { kmin[c] = smin[0][c]; kmax[c] = smax[0][c]; }
        for (int w = 1; w < nw; w++) {
            #pragma unroll
            for (int c = 0; c < 3; c++) {
                kmin[c] = kmin[c] < smin[w][c] ? kmin[c] : smin[w][c];
                kmax[c] = kmax[c] > smax[w][c] ? kmax[c] : smax[w][c];
            }
        }
        #pragma unroll
        for (int c = 0; c < 3; c++) {
            atomicMin(&keys[c], kmin[c]);
            atomicMax(&keys[3 + c], kmax[c]);
        }
    }
}

__device__ __forceinline__ int atom_cell(float x, float y, float z,
                                         const unsigned* __restrict__ keys) {
    float mnx = funkey(keys[0]), mny = funkey(keys[1]), mnz = funkey(keys[2]);
    float mxx = funkey(keys[3]), mxy = funkey(keys[4]), mxz = funkey(keys[5]);
    // exact op-order of reference: (x - min) / (max - min) * 47, f32, truncate
    int cx = (int)((x - mnx) / (mxx - mnx) * 47.0f);
    int cy = (int)((y - mny) / (mxy - mny) * 47.0f);
    int cz = (int)((z - mnz) / (mxz - mnz) * 47.0f);
    return (cz * VOL + cy) * VOL + cx;
}

// ---- stage 2a: scatter into hashed planes (kills same-line clustering) ----
__global__ void vox_scatter_h(const float* __restrict__ xyz,
                              const float* __restrict__ feat, int n,
                              const unsigned* __restrict__ keys,
                              float* __restrict__ centerH) {
    int i = blockIdx.x * blockDim.x + threadIdx.x;
    if (i >= n) return;
    float x = xyz[3 * i + 0], y = xyz[3 * i + 1], z = xyz[3 * i + 2];
    if (x == 0.f || y == 0.f || z == 0.f) return;
    unsigned h = hcell(atom_cell(x, y, z, keys));
    const float* fr = feat + (size_t)i * FEATD;
    #pragma unroll
    for (int f = 0; f < FEATD; f++)
        atomicAdd(&centerH[(unsigned)f * HPLANE + h], fr[f]);
}

// ---- stage 2b (fallback): direct scatter into linear grid ----
__global__ void vox_scatter_lin(const float* __restrict__ xyz,
                                const float* __restrict__ feat, int n,
                                const unsigned* __restrict__ keys,
                                float* __restrict__ center) {
    int i = blockIdx.x * blockDim.x + threadIdx.x;
    if (i >= n) return;
    float x = xyz[3 * i + 0], y = xyz[3 * i + 1], z = xyz[3 * i + 2];
    if (x == 0.f || y == 0.f || z == 0.f) return;
    int cell = atom_cell(x, y, z, keys);
    const float* fr = feat + (size_t)i * FEATD;
    #pragma unroll
    for (int f = 0; f < FEATD; f++)
        atomicAdd(&center[f * VOL3 + cell], fr[f]);
}

// ---- stage 3: unhash into linear [f][cell] grid ----
__global__ void vox_remap(const float* __restrict__ centerH,
                          float* __restrict__ centerL) {
    int cell = blockIdx.x * blockDim.x + threadIdx.x;
    int f = blockIdx.y;
    if (cell >= VOL3) return;
    centerL[(size_t)f * VOL3 + cell] = centerH[(unsigned)f * HPLANE + hcell(cell)];
}

// ---- stage 4: 3x3x3 box convolution ----
__global__ void vox_conv(const float* __restrict__ center,
                         float* __restrict__ out, int total) {
    int idx = blockIdx.x * blockDim.x + threadIdx.x;
    if (idx >= total) return;
    int x = idx % VOL;
    int t = idx / VOL;
    int y = t % VOL;  t /= VOL;
    int z = t % VOL;
    int f = t / VOL;
    const float* cf = center + (size_t)f * VOL3;
    float s = 0.f;
    for (int dz = -1; dz <= 1; dz++) {
        int zz = z + dz; if ((unsigned)zz >= (unsigned)VOL) continue;
        for (int dy = -1; dy <= 1; dy++) {
            int yy = y + dy; if ((unsigned)yy >= (unsigned)VOL) continue;
            const float* row = cf + (zz * VOL + yy) * VOL;
            #pragma unroll
            for (int dx = -1; dx <= 1; dx++) {
                int xx = x + dx; if ((unsigned)xx >= (unsigned)VOL) continue;
                s += row[xx];
            }
        }
    }
    out[idx] = s;
}

extern "C" void kernel_launch(void* const* d_in, const int* in_sizes, int n_in,
                              void* d_out, int out_size, void* d_ws, size_t ws_size,
                              hipStream_t stream) {
    const float* xyz  = (const float*)d_in[0];
    const float* feat = (const float*)d_in[1];
    float* out = (float*)d_out;
    int n = in_sizes[0] / 3;

    unsigned* keys = (unsigned*)d_ws;
    float* centerH = (float*)((char*)d_ws + 256);
    size_t hbytes = (size_t)FEATD * HPLANE * sizeof(float);          // ~9.96 MB
    float* centerL = (float*)((char*)d_ws + 256 + hbytes);
    size_t need = 256 + hbytes + (size_t)FEATD * VOL3 * sizeof(float);

    // workspace re-init every call (harness does not re-poison)
    hipMemsetAsync(keys, 0xFF, 3 * sizeof(unsigned), stream);
    hipMemsetAsync(keys + 3, 0x00, 3 * sizeof(unsigned), stream);

    vox_minmax<<<64, 1024, 0, stream>>>(xyz, n, keys);

    const int b = 256;
    const int total = FEATD * VOL3;
    if (ws_size >= need) {
        hipMemsetAsync(centerH, 0, hbytes, stream);
        vox_scatter_h<<<(n + b - 1) / b, b, 0, stream>>>(xyz, feat, n, keys, centerH);
        dim3 rg((VOL3 + b - 1) / b, FEATD);
        vox_remap<<<rg, b, 0, stream>>>(centerH, centerL);
        vox_conv<<<(total + b - 1) / b, b, 0, stream>>>(centerL, out, total);
    } else {
        float* center = (float*)((char*)d_ws + 256);
        hipMemsetAsync(center, 0, (size_t)FEATD * VOL3 * sizeof(float), stream);
        vox_scatter_lin<<<(n + b - 1) / b, b, 0, stream>>>(xyz, feat, n, keys, center);
        vox_conv<<<(total + b - 1) / b, b, 0, stream>>>(center, out, total);
    }
}